// Round 1
// baseline (3156.555 us; speedup 1.0000x reference)
//
#include <hip/hip_runtime.h>
#include <math.h>

// Problem dims (fixed)
#define B_ 4
#define T_ 1024
#define C_ 256
#define D_ 256
#define H_ 512
#define NH_ 8
#define HD_ 64
#define INTER_ 2048
#define L_ 4
#define CB_ 128   // context_backward; context_forward = 0

__device__ __forceinline__ float gelu_exact(float x) {
    return 0.5f * x * (1.0f + erff(x * 0.70710678118654752f));
}

// ---------------------------------------------------------------------------
// Generic fp32 GEMM: C[M,N] = act(A[M,K] @ B[K,N] + bias[N]) (+ res[M,N])
// BM=BN=64, BK=16, 256 threads, 4x4 micro-tile per thread.
// Requires M%64==0, N%64==0, K%16==0 (true for all shapes here).
// ---------------------------------------------------------------------------
template<int ACT, int RES>
__global__ __launch_bounds__(256) void gemm_k(
    const float* __restrict__ A, const float* __restrict__ Bm,
    const float* __restrict__ bias, const float* __restrict__ res,
    float* __restrict__ C, int M, int N, int K)
{
    __shared__ float As[16][64];  // [k][m]
    __shared__ float Bs[16][64];  // [k][n]

    const int tid = threadIdx.x;
    const int tx = tid & 15;       // micro col group
    const int ty = tid >> 4;       // micro row group
    const int bx = blockIdx.x;     // N tile
    const int by = blockIdx.y;     // M tile

    // A-load mapping: thread -> (row 0..63, 4 consecutive k)
    const int a_row = tid >> 2;
    const int a_k   = (tid & 3) << 2;
    // B-load mapping: thread -> (k-row 0..15, 4 consecutive n)
    const int b_row = tid >> 4;
    const int b_col = (tid & 15) << 2;

    float acc[4][4] = {};

    const float* Aptr = A + (size_t)(by * 64 + a_row) * K + a_k;
    const float* Bptr = Bm + (size_t)b_row * N + bx * 64 + b_col;

    for (int k0 = 0; k0 < K; k0 += 16) {
        float4 av = *(const float4*)(Aptr + k0);
        As[a_k + 0][a_row] = av.x;
        As[a_k + 1][a_row] = av.y;
        As[a_k + 2][a_row] = av.z;
        As[a_k + 3][a_row] = av.w;
        float4 bv = *(const float4*)(Bptr + (size_t)k0 * N);
        *(float4*)&Bs[b_row][b_col] = bv;
        __syncthreads();

#pragma unroll
        for (int kk = 0; kk < 16; ++kk) {
            float4 a4 = *(const float4*)&As[kk][ty << 2];
            float4 b4 = *(const float4*)&Bs[kk][tx << 2];
            float ar[4] = {a4.x, a4.y, a4.z, a4.w};
            float br[4] = {b4.x, b4.y, b4.z, b4.w};
#pragma unroll
            for (int i = 0; i < 4; ++i)
#pragma unroll
                for (int j = 0; j < 4; ++j)
                    acc[i][j] += ar[i] * br[j];
        }
        __syncthreads();
    }

    const int row0 = by * 64 + (ty << 2);
    const int col0 = bx * 64 + (tx << 2);
#pragma unroll
    for (int i = 0; i < 4; ++i) {
#pragma unroll
        for (int j = 0; j < 4; ++j) {
            float c = acc[i][j] + bias[col0 + j];
            if (ACT == 1) c = gelu_exact(c);
            if (RES) c += res[(size_t)(row0 + i) * N + col0 + j];
            C[(size_t)(row0 + i) * N + col0 + j] = c;
        }
    }
}

// ---------------------------------------------------------------------------
// LayerNorm over H=512. One 256-thread block per row; 2 elements per thread.
// Two-pass (mean, then variance of deviations) to match reference numerics.
// ---------------------------------------------------------------------------
__global__ __launch_bounds__(256) void ln_k(
    const float* __restrict__ x, const float* __restrict__ g,
    const float* __restrict__ b, float* __restrict__ out)
{
    const int row = blockIdx.x;
    const int tid = threadIdx.x;
    const float* xr = x + (size_t)row * H_;

    float v0 = xr[tid];
    float v1 = xr[tid + 256];

    float s = v0 + v1;
#pragma unroll
    for (int off = 32; off; off >>= 1) s += __shfl_xor(s, off);

    __shared__ float red[4];
    const int wave = tid >> 6;
    if ((tid & 63) == 0) red[wave] = s;
    __syncthreads();
    const float mean = (red[0] + red[1] + red[2] + red[3]) * (1.0f / (float)H_);

    const float d0 = v0 - mean, d1 = v1 - mean;
    float q = d0 * d0 + d1 * d1;
#pragma unroll
    for (int off = 32; off; off >>= 1) q += __shfl_xor(q, off);
    __syncthreads();
    if ((tid & 63) == 0) red[wave] = q;
    __syncthreads();
    const float var = (red[0] + red[1] + red[2] + red[3]) * (1.0f / (float)H_);
    const float rstd = rsqrtf(var + 1e-5f);

    out[(size_t)row * H_ + tid]       = d0 * rstd * g[tid] + b[tid];
    out[(size_t)row * H_ + tid + 256] = d1 * rstd * g[tid + 256] + b[tid + 256];
}

// ---------------------------------------------------------------------------
// RoPE applied in-place to q and k (layout [B,T,H] = [B,T,NH*HD]).
// idx enumerates (b, t, nh, d) with d in [0,32); pairs (d, d+32).
// ---------------------------------------------------------------------------
__global__ __launch_bounds__(256) void rope_k(
    float* __restrict__ q, float* __restrict__ k, const int* __restrict__ ts)
{
    const int idx = blockIdx.x * 256 + threadIdx.x;  // B*T*NH*32 total
    const int d  = idx & 31;
    const int nh = (idx >> 5) & (NH_ - 1);
    const int t  = (idx >> 8) & (T_ - 1);
    const int b  = idx >> 18;

    const int tstamp = ts[b * T_ + t];
    // inv = 10000^(-2d/64) = exp(-ln(10000)/32 * d)
    const float inv = expf(-0.2878231366242558f * (float)d);
    const float ang = (float)tstamp * inv;
    const float c = cosf(ang);
    const float s = sinf(ang);

    const size_t base = ((size_t)(b * T_ + t)) * H_ + nh * HD_ + d;
    float q1 = q[base], q2 = q[base + 32];
    q[base]      = q1 * c - q2 * s;
    q[base + 32] = q2 * c + q1 * s;
    float k1 = k[base], k2 = k[base + 32];
    k[base]      = k1 * c - k2 * s;
    k[base + 32] = k2 * c + k1 * s;
}

// ---------------------------------------------------------------------------
// Banded attention: one 64-lane wave per (b, head, query i). lane = dim d.
// Window j in [max(0,i-CB), i]. Scores in LDS, softmax, PV accumulate.
// q already scaled is not assumed: scale applied here (1/sqrt(64)).
// ---------------------------------------------------------------------------
__global__ __launch_bounds__(64) void attn_k(
    const float* __restrict__ q, const float* __restrict__ k,
    const float* __restrict__ v, const int* __restrict__ smask,
    float* __restrict__ o)
{
    const int gid = blockIdx.x;
    const int i = gid & (T_ - 1);
    const int h = (gid >> 10) & (NH_ - 1);
    const int b = gid >> 13;
    const int d = threadIdx.x;

    __shared__ float s[CB_ + 8];

    const float qd = q[((size_t)(b * T_ + i)) * H_ + h * HD_ + d] * 0.125f;
    const int jlo = (i - CB_ > 0) ? (i - CB_) : 0;
    const int cnt = i - jlo + 1;

    const float* kb = k + (size_t)(b * T_) * H_ + h * HD_;
    const float* vb = v + (size_t)(b * T_) * H_ + h * HD_;

    // pass 1: scores
    for (int jj = 0; jj < cnt; ++jj) {
        const int j = jlo + jj;
        float p = qd * kb[(size_t)j * H_ + d];
#pragma unroll
        for (int off = 32; off; off >>= 1) p += __shfl_xor(p, off);
        if (d == 0) s[jj] = (smask[b * T_ + j] > 0) ? p : -3.4e38f;
    }
    __syncthreads();

    // softmax over s[0..cnt)
    float mx = -3.4e38f;
    for (int jj = d; jj < cnt; jj += 64) mx = fmaxf(mx, s[jj]);
#pragma unroll
    for (int off = 32; off; off >>= 1) mx = fmaxf(mx, __shfl_xor(mx, off));

    float sum = 0.0f;
    for (int jj = d; jj < cnt; jj += 64) {
        float e = expf(s[jj] - mx);
        s[jj] = e;
        sum += e;
    }
#pragma unroll
    for (int off = 32; off; off >>= 1) sum += __shfl_xor(sum, off);
    __syncthreads();

    const float invsum = 1.0f / sum;

    // pass 2: o_d = sum_j p_j * v[j][d]
    float od = 0.0f;
    for (int jj = 0; jj < cnt; ++jj)
        od += s[jj] * vb[(size_t)(jlo + jj) * H_ + d];

    o[((size_t)(b * T_ + i)) * H_ + h * HD_ + d] = od * invsum;
}

// ---------------------------------------------------------------------------
extern "C" void kernel_launch(void* const* d_in, const int* in_sizes, int n_in,
                              void* d_out, int out_size, void* d_ws, size_t ws_size,
                              hipStream_t stream)
{
    const float* spikes  = (const float*)d_in[0];
    const int*   smask   = (const int*)d_in[1];
    const int*   ts      = (const int*)d_in[2];
    const float* embed_w = (const float*)d_in[3];
    const float* embed_b = (const float*)d_in[4];
    const float* proj_w  = (const float*)d_in[5];
    const float* proj_b  = (const float*)d_in[6];
    const float* ln1_g   = (const float*)d_in[7];
    const float* ln1_b   = (const float*)d_in[8];
    const float* Wq      = (const float*)d_in[9];
    const float* bq      = (const float*)d_in[10];
    const float* Wk      = (const float*)d_in[11];
    const float* bk      = (const float*)d_in[12];
    const float* Wv      = (const float*)d_in[13];
    const float* bv      = (const float*)d_in[14];
    const float* Wo      = (const float*)d_in[15];
    const float* bo      = (const float*)d_in[16];
    const float* ln2_g   = (const float*)d_in[17];
    const float* ln2_b   = (const float*)d_in[18];
    const float* up_w    = (const float*)d_in[19];
    const float* up_b    = (const float*)d_in[20];
    const float* down_w  = (const float*)d_in[21];
    const float* down_b  = (const float*)d_in[22];

    const int M = B_ * T_;            // 4096
    float* ws = (float*)d_ws;
    float* x     = ws;                 // 4096*512  = 2,097,152
    float* hbuf  = x     + 2097152;    // 2,097,152
    float* qbuf  = hbuf  + 2097152;    // 2,097,152
    float* kbuf  = qbuf  + 2097152;    // 2,097,152
    float* vbuf  = kbuf  + 2097152;    // 2,097,152
    float* obuf  = vbuf  + 2097152;    // 2,097,152
    float* inter = obuf  + 2097152;    // 4096*2048 = 8,388,608
    float* tmp   = inter + 8388608;    // 4096*256  = 1,048,576
    // total ~22.0M floats = 88 MB of d_ws

    // Embedding: tmp = gelu(spikes @ embed_w + embed_b); x = tmp @ proj_w + proj_b
    gemm_k<1, 0><<<dim3(D_ / 64, M / 64), 256, 0, stream>>>(
        spikes, embed_w, embed_b, nullptr, tmp, M, D_, C_);
    gemm_k<0, 0><<<dim3(H_ / 64, M / 64), 256, 0, stream>>>(
        tmp, proj_w, proj_b, nullptr, x, M, H_, D_);

    for (int l = 0; l < L_; ++l) {
        const float* Wq_l = Wq + (size_t)l * H_ * H_;
        const float* Wk_l = Wk + (size_t)l * H_ * H_;
        const float* Wv_l = Wv + (size_t)l * H_ * H_;
        const float* Wo_l = Wo + (size_t)l * H_ * H_;
        const float* up_w_l   = up_w   + (size_t)l * H_ * INTER_;
        const float* down_w_l = down_w + (size_t)l * INTER_ * H_;

        // h = LN1(x)
        ln_k<<<M, 256, 0, stream>>>(x, ln1_g + l * H_, ln1_b + l * H_, hbuf);

        // q,k,v projections (layout [B,T,H])
        gemm_k<0, 0><<<dim3(H_ / 64, M / 64), 256, 0, stream>>>(
            hbuf, Wq_l, bq + l * H_, nullptr, qbuf, M, H_, H_);
        gemm_k<0, 0><<<dim3(H_ / 64, M / 64), 256, 0, stream>>>(
            hbuf, Wk_l, bk + l * H_, nullptr, kbuf, M, H_, H_);
        gemm_k<0, 0><<<dim3(H_ / 64, M / 64), 256, 0, stream>>>(
            hbuf, Wv_l, bv + l * H_, nullptr, vbuf, M, H_, H_);

        // RoPE in place on q,k
        rope_k<<<(B_ * T_ * NH_ * 32) / 256, 256, 0, stream>>>(qbuf, kbuf, ts);

        // banded attention -> obuf
        attn_k<<<B_ * NH_ * T_, 64, 0, stream>>>(qbuf, kbuf, vbuf, smask, obuf);

        // x = x + obuf @ Wo + bo
        gemm_k<0, 1><<<dim3(H_ / 64, M / 64), 256, 0, stream>>>(
            obuf, Wo_l, bo + l * H_, x, x, M, H_, H_);

        // h = LN2(x)
        ln_k<<<M, 256, 0, stream>>>(x, ln2_g + l * H_, ln2_b + l * H_, hbuf);

        // inter = gelu(h @ up_w + up_b)
        gemm_k<1, 0><<<dim3(INTER_ / 64, M / 64), 256, 0, stream>>>(
            hbuf, up_w_l, up_b + l * INTER_, nullptr, inter, M, INTER_, H_);

        // x = x + inter @ down_w + down_b   (last layer writes d_out)
        float* dst = (l == L_ - 1) ? (float*)d_out : x;
        gemm_k<0, 1><<<dim3(H_ / 64, M / 64), 256, 0, stream>>>(
            inter, down_w_l, down_b + l * H_, x, dst, M, H_, INTER_);
    }
}

// Round 2
// 2128.009 us; speedup vs baseline: 1.4833x; 1.4833x over previous
//
#include <hip/hip_runtime.h>
#include <math.h>

// Problem dims (fixed)
#define B_ 4
#define T_ 1024
#define C_ 256
#define D_ 256
#define H_ 512
#define NH_ 8
#define HD_ 64
#define INTER_ 2048
#define L_ 4
#define CB_ 128   // context_backward; context_forward = 0

__device__ __forceinline__ float gelu_exact(float x) {
    return 0.5f * x * (1.0f + erff(x * 0.70710678118654752f));
}

// ---------------------------------------------------------------------------
// Generic fp32 GEMM: C[M,N] = act(A[M,K] @ B[K,N] + bias[N]) (+ res[M,N])
// BM=BN=64, BK=16, 256 threads, 4x4 micro-tile per thread.
// ---------------------------------------------------------------------------
template<int ACT, int RES>
__global__ __launch_bounds__(256) void gemm_k(
    const float* __restrict__ A, const float* __restrict__ Bm,
    const float* __restrict__ bias, const float* __restrict__ res,
    float* __restrict__ C, int M, int N, int K)
{
    __shared__ float As[16][64];  // [k][m]
    __shared__ float Bs[16][64];  // [k][n]

    const int tid = threadIdx.x;
    const int tx = tid & 15;
    const int ty = tid >> 4;
    const int bx = blockIdx.x;
    const int by = blockIdx.y;

    const int a_row = tid >> 2;
    const int a_k   = (tid & 3) << 2;
    const int b_row = tid >> 4;
    const int b_col = (tid & 15) << 2;

    float acc[4][4] = {};

    const float* Aptr = A + (size_t)(by * 64 + a_row) * K + a_k;
    const float* Bptr = Bm + (size_t)b_row * N + bx * 64 + b_col;

    for (int k0 = 0; k0 < K; k0 += 16) {
        float4 av = *(const float4*)(Aptr + k0);
        As[a_k + 0][a_row] = av.x;
        As[a_k + 1][a_row] = av.y;
        As[a_k + 2][a_row] = av.z;
        As[a_k + 3][a_row] = av.w;
        float4 bv = *(const float4*)(Bptr + (size_t)k0 * N);
        *(float4*)&Bs[b_row][b_col] = bv;
        __syncthreads();

#pragma unroll
        for (int kk = 0; kk < 16; ++kk) {
            float4 a4 = *(const float4*)&As[kk][ty << 2];
            float4 b4 = *(const float4*)&Bs[kk][tx << 2];
            float ar[4] = {a4.x, a4.y, a4.z, a4.w};
            float br[4] = {b4.x, b4.y, b4.z, b4.w};
#pragma unroll
            for (int i = 0; i < 4; ++i)
#pragma unroll
                for (int j = 0; j < 4; ++j)
                    acc[i][j] += ar[i] * br[j];
        }
        __syncthreads();
    }

    const int row0 = by * 64 + (ty << 2);
    const int col0 = bx * 64 + (tx << 2);
#pragma unroll
    for (int i = 0; i < 4; ++i) {
#pragma unroll
        for (int j = 0; j < 4; ++j) {
            float c = acc[i][j] + bias[col0 + j];
            if (ACT == 1) c = gelu_exact(c);
            if (RES) c += res[(size_t)(row0 + i) * N + col0 + j];
            C[(size_t)(row0 + i) * N + col0 + j] = c;
        }
    }
}

// ---------------------------------------------------------------------------
// LayerNorm over H=512.
// ---------------------------------------------------------------------------
__global__ __launch_bounds__(256) void ln_k(
    const float* __restrict__ x, const float* __restrict__ g,
    const float* __restrict__ b, float* __restrict__ out)
{
    const int row = blockIdx.x;
    const int tid = threadIdx.x;
    const float* xr = x + (size_t)row * H_;

    float v0 = xr[tid];
    float v1 = xr[tid + 256];

    float s = v0 + v1;
#pragma unroll
    for (int off = 32; off; off >>= 1) s += __shfl_xor(s, off);

    __shared__ float red[4];
    const int wave = tid >> 6;
    if ((tid & 63) == 0) red[wave] = s;
    __syncthreads();
    const float mean = (red[0] + red[1] + red[2] + red[3]) * (1.0f / (float)H_);

    const float d0 = v0 - mean, d1 = v1 - mean;
    float q = d0 * d0 + d1 * d1;
#pragma unroll
    for (int off = 32; off; off >>= 1) q += __shfl_xor(q, off);
    __syncthreads();
    if ((tid & 63) == 0) red[wave] = q;
    __syncthreads();
    const float var = (red[0] + red[1] + red[2] + red[3]) * (1.0f / (float)H_);
    const float rstd = rsqrtf(var + 1e-5f);

    out[(size_t)row * H_ + tid]       = d0 * rstd * g[tid] + b[tid];
    out[(size_t)row * H_ + tid + 256] = d1 * rstd * g[tid + 256] + b[tid + 256];
}

// ---------------------------------------------------------------------------
// RoPE applied in-place to q and k (layout [B,T,H]).
// ---------------------------------------------------------------------------
__global__ __launch_bounds__(256) void rope_k(
    float* __restrict__ q, float* __restrict__ k, const int* __restrict__ ts)
{
    const int idx = blockIdx.x * 256 + threadIdx.x;  // B*T*NH*32 total
    const int d  = idx & 31;
    const int nh = (idx >> 5) & (NH_ - 1);
    const int t  = (idx >> 8) & (T_ - 1);
    const int b  = idx >> 18;

    const int tstamp = ts[b * T_ + t];
    const float inv = expf(-0.2878231366242558f * (float)d);
    const float ang = (float)tstamp * inv;
    const float c = cosf(ang);
    const float s = sinf(ang);

    const size_t base = ((size_t)(b * T_ + t)) * H_ + nh * HD_ + d;
    float q1 = q[base], q2 = q[base + 32];
    q[base]      = q1 * c - q2 * s;
    q[base + 32] = q2 * c + q1 * s;
    float k1 = k[base], k2 = k[base + 32];
    k[base]      = k1 * c - k2 * s;
    k[base + 32] = k2 * c + k1 * s;
}

// ---------------------------------------------------------------------------
// Banded attention v2: one 256-thread block per (b, head, 16-query tile).
// K-window + scaled Q staged in LDS (pad 68 floats -> conflict-free float4).
// Scores: threads flattened over (query, window-pos); 64-FMA dot each, no
// shuffles. Softmax: one wave per 4 query rows. PV: lane=d, one coalesced
// v-row load feeds 4 query FMAs. Out-of-band score slots pre-zeroed so PV
// scans a uniform window.
// ---------------------------------------------------------------------------
#define QT_ 16           // queries per block
#define WR_ (QT_ + CB_)  // max staged window rows = 144
#define KP_ 68           // padded row stride for Ks/Qs

__global__ __launch_bounds__(256) void attn_k(
    const float* __restrict__ q, const float* __restrict__ k,
    const float* __restrict__ v, const int* __restrict__ smask,
    float* __restrict__ o)
{
    __shared__ float Ks[WR_][KP_];
    __shared__ float Qs[QT_][KP_];
    __shared__ float S[QT_][WR_ + 2];

    const int blk = blockIdx.x;
    const int qt = blk & (T_ / QT_ - 1);        // 64 tiles
    const int h  = (blk >> 6) & (NH_ - 1);
    const int b  = blk >> 9;
    const int tid = threadIdx.x;

    const int qlo = qt * QT_;
    const int klo = (qlo - CB_ > 0) ? (qlo - CB_) : 0;
    const int nrows = qlo + QT_ - klo;          // <= 144

    const size_t bhbase = (size_t)(b * T_) * H_ + h * HD_;

    // stage K window (coalesced: one 256B row per wave-iteration)
    for (int idx = tid; idx < nrows * 64; idx += 256) {
        const int r = idx >> 6, d = idx & 63;
        Ks[r][d] = k[bhbase + (size_t)(klo + r) * H_ + d];
    }
    // stage scaled Q
    for (int idx = tid; idx < QT_ * 64; idx += 256) {
        const int iq = idx >> 6, d = idx & 63;
        Qs[iq][d] = q[bhbase + (size_t)(qlo + iq) * H_ + d] * 0.125f;
    }
    // zero score buffer (out-of-band slots must read as 0 in PV)
    {
        float* Sf = &S[0][0];
        for (int idx = tid; idx < QT_ * (WR_ + 2); idx += 256) Sf[idx] = 0.0f;
    }
    __syncthreads();

    // score pass: flatten (iq, rr) pairs, rr in [0,129) -> j = i-128+rr
    const int npairs = QT_ * (CB_ + 1);         // 16*129 = 2064
    for (int p = tid; p < npairs; p += 256) {
        const int iq = p / (CB_ + 1);
        const int rr = p - iq * (CB_ + 1);
        const int i  = qlo + iq;
        const int j  = i - CB_ + rr;
        if (j < 0) continue;
        const int r = j - klo;
        float acc = 0.0f;
        const float* kr = &Ks[r][0];
        const float* qr = &Qs[iq][0];
#pragma unroll
        for (int dq = 0; dq < 16; ++dq) {
            float4 kv = *(const float4*)(kr + dq * 4);
            float4 qv = *(const float4*)(qr + dq * 4);
            acc += kv.x * qv.x + kv.y * qv.y + kv.z * qv.z + kv.w * qv.w;
        }
        S[iq][r] = (smask[b * T_ + j] > 0) ? acc : -3.4e38f;
    }
    __syncthreads();

    // softmax + PV: wave w owns queries iq = 4w..4w+3
    const int w = tid >> 6;
    const int lane = tid & 63;

    float rs[4];   // inv-sum per owned query
#pragma unroll
    for (int c = 0; c < 4; ++c) {
        const int iq = w * 4 + c;
        const int i  = qlo + iq;
        const int r0 = ((i - CB_ > 0) ? (i - CB_) : 0) - klo;
        const int r1 = i - klo;

        float mx = -3.4e38f;
        for (int r = r0 + lane; r <= r1; r += 64) mx = fmaxf(mx, S[iq][r]);
#pragma unroll
        for (int off = 32; off; off >>= 1) mx = fmaxf(mx, __shfl_xor(mx, off));

        float sum = 0.0f;
        for (int r = r0 + lane; r <= r1; r += 64) {
            float e = expf(S[iq][r] - mx);
            S[iq][r] = e;
            sum += e;
        }
#pragma unroll
        for (int off = 32; off; off >>= 1) sum += __shfl_xor(sum, off);
        rs[c] = 1.0f / sum;
    }

    // PV: lane = d; one coalesced v-row load feeds 4 query accumulators
    float od[4] = {0.0f, 0.0f, 0.0f, 0.0f};
    const float* vb = v + bhbase + lane;
    for (int r = 0; r < nrows; ++r) {
        const float vv = vb[(size_t)(klo + r) * H_];
#pragma unroll
        for (int c = 0; c < 4; ++c)
            od[c] += S[w * 4 + c][r] * vv;
    }
#pragma unroll
    for (int c = 0; c < 4; ++c) {
        const int i = qlo + w * 4 + c;
        o[bhbase + (size_t)i * H_ + lane] = od[c] * rs[c];
    }
}

// ---------------------------------------------------------------------------
extern "C" void kernel_launch(void* const* d_in, const int* in_sizes, int n_in,
                              void* d_out, int out_size, void* d_ws, size_t ws_size,
                              hipStream_t stream)
{
    const float* spikes  = (const float*)d_in[0];
    const int*   smask   = (const int*)d_in[1];
    const int*   ts      = (const int*)d_in[2];
    const float* embed_w = (const float*)d_in[3];
    const float* embed_b = (const float*)d_in[4];
    const float* proj_w  = (const float*)d_in[5];
    const float* proj_b  = (const float*)d_in[6];
    const float* ln1_g   = (const float*)d_in[7];
    const float* ln1_b   = (const float*)d_in[8];
    const float* Wq      = (const float*)d_in[9];
    const float* bq      = (const float*)d_in[10];
    const float* Wk      = (const float*)d_in[11];
    const float* bk      = (const float*)d_in[12];
    const float* Wv      = (const float*)d_in[13];
    const float* bv      = (const float*)d_in[14];
    const float* Wo      = (const float*)d_in[15];
    const float* bo      = (const float*)d_in[16];
    const float* ln2_g   = (const float*)d_in[17];
    const float* ln2_b   = (const float*)d_in[18];
    const float* up_w    = (const float*)d_in[19];
    const float* up_b    = (const float*)d_in[20];
    const float* down_w  = (const float*)d_in[21];
    const float* down_b  = (const float*)d_in[22];

    const int M = B_ * T_;            // 4096
    float* ws = (float*)d_ws;
    float* x     = ws;
    float* hbuf  = x     + 2097152;
    float* qbuf  = hbuf  + 2097152;
    float* kbuf  = qbuf  + 2097152;
    float* vbuf  = kbuf  + 2097152;
    float* obuf  = vbuf  + 2097152;
    float* inter = obuf  + 2097152;
    float* tmp   = inter + 8388608;

    gemm_k<1, 0><<<dim3(D_ / 64, M / 64), 256, 0, stream>>>(
        spikes, embed_w, embed_b, nullptr, tmp, M, D_, C_);
    gemm_k<0, 0><<<dim3(H_ / 64, M / 64), 256, 0, stream>>>(
        tmp, proj_w, proj_b, nullptr, x, M, H_, D_);

    for (int l = 0; l < L_; ++l) {
        const float* Wq_l = Wq + (size_t)l * H_ * H_;
        const float* Wk_l = Wk + (size_t)l * H_ * H_;
        const float* Wv_l = Wv + (size_t)l * H_ * H_;
        const float* Wo_l = Wo + (size_t)l * H_ * H_;
        const float* up_w_l   = up_w   + (size_t)l * H_ * INTER_;
        const float* down_w_l = down_w + (size_t)l * INTER_ * H_;

        ln_k<<<M, 256, 0, stream>>>(x, ln1_g + l * H_, ln1_b + l * H_, hbuf);

        gemm_k<0, 0><<<dim3(H_ / 64, M / 64), 256, 0, stream>>>(
            hbuf, Wq_l, bq + l * H_, nullptr, qbuf, M, H_, H_);
        gemm_k<0, 0><<<dim3(H_ / 64, M / 64), 256, 0, stream>>>(
            hbuf, Wk_l, bk + l * H_, nullptr, kbuf, M, H_, H_);
        gemm_k<0, 0><<<dim3(H_ / 64, M / 64), 256, 0, stream>>>(
            hbuf, Wv_l, bv + l * H_, nullptr, vbuf, M, H_, H_);

        rope_k<<<(B_ * T_ * NH_ * 32) / 256, 256, 0, stream>>>(qbuf, kbuf, ts);

        attn_k<<<B_ * NH_ * (T_ / QT_), 256, 0, stream>>>(qbuf, kbuf, vbuf, smask, obuf);

        gemm_k<0, 1><<<dim3(H_ / 64, M / 64), 256, 0, stream>>>(
            obuf, Wo_l, bo + l * H_, x, x, M, H_, H_);

        ln_k<<<M, 256, 0, stream>>>(x, ln2_g + l * H_, ln2_b + l * H_, hbuf);

        gemm_k<1, 0><<<dim3(INTER_ / 64, M / 64), 256, 0, stream>>>(
            hbuf, up_w_l, up_b + l * INTER_, nullptr, inter, M, INTER_, H_);

        float* dst = (l == L_ - 1) ? (float*)d_out : x;
        gemm_k<0, 1><<<dim3(H_ / 64, M / 64), 256, 0, stream>>>(
            inter, down_w_l, down_b + l * H_, x, dst, M, H_, INTER_);
    }
}

// Round 3
// 1015.672 us; speedup vs baseline: 3.1078x; 2.0952x over previous
//
#include <hip/hip_runtime.h>
#include <math.h>

// Problem dims (fixed)
#define B_ 4
#define T_ 1024
#define C_ 256
#define D_ 256
#define H_ 512
#define NH_ 8
#define HD_ 64
#define INTER_ 2048
#define L_ 4
#define CB_ 128   // context_backward; context_forward = 0

typedef unsigned short ushort16_t;
typedef short bf16x8 __attribute__((ext_vector_type(8)));
typedef float f32x4 __attribute__((ext_vector_type(4)));

__device__ __forceinline__ float gelu_exact(float x) {
    return 0.5f * x * (1.0f + erff(x * 0.70710678118654752f));
}

// fp32 -> bf16 round-to-nearest-even
__device__ __forceinline__ unsigned short f2bf(float f) {
    unsigned u = __float_as_uint(f);
    u += 0x7fffu + ((u >> 16) & 1u);
    return (unsigned short)(u >> 16);
}

// ---------------------------------------------------------------------------
// bf16 MFMA GEMM: out[M,N] = epi(A[M,K](bf16) @ BT[N,K](bf16)^T + bias)
// 128x128 tile, 256 threads (4 waves in 2x2), each wave 4x4 grid of
// 16x16x32 bf16 MFMA. BK=32. global_load_lds width-16 staging.
// SPLIT=1: N is 3x512 (QKV fused); route output/bias by global col >> 9.
// ---------------------------------------------------------------------------
template<int ACT, int RES, int OBF, int SPLIT>
__global__ __launch_bounds__(256) void mm_k(
    const unsigned short* __restrict__ A, const unsigned short* __restrict__ BT,
    const float* __restrict__ b0, const float* __restrict__ b1,
    const float* __restrict__ b2,
    const float* res,
    void* o0, void* o1, void* o2,
    const int M, const int N, const int K)
{
    __shared__ unsigned short As[128 * 32];
    __shared__ unsigned short Bs[128 * 32];

    const int tid  = threadIdx.x;
    const int lane = tid & 63;
    const int w    = tid >> 6;
    const int m0   = blockIdx.y * 128;
    const int n0   = blockIdx.x * 128;
    const int wm   = (w >> 1) * 64;
    const int wn   = (w & 1) * 64;
    const int frow = lane & 15;
    const int fk   = (lane >> 4) * 8;

    f32x4 acc[4][4] = {};

    // staging chunk ids (16B chunks; tile = 512 chunks = 8KB)
    const int c0 = (w << 6) + lane;   // issue 0: 0..255
    const int c1 = c0 + 256;          // issue 1: 256..511

    const unsigned short* Abase = A  + (size_t)m0 * K;
    const unsigned short* Bbase = BT + (size_t)n0 * K;

    for (int k0 = 0; k0 < K; k0 += 32) {
        __syncthreads();
        // A tile: chunk c -> row c>>2, 8-elem group c&3. LDS = [row][k] packed.
        {
            const unsigned short* ga0 = Abase + (size_t)(c0 >> 2) * K + k0 + (c0 & 3) * 8;
            const unsigned short* ga1 = Abase + (size_t)(c1 >> 2) * K + k0 + (c1 & 3) * 8;
            __builtin_amdgcn_global_load_lds(
                (const __attribute__((address_space(1))) unsigned*)ga0,
                (__attribute__((address_space(3))) unsigned*)(As + (size_t)(w << 6) * 8), 16, 0, 0);
            __builtin_amdgcn_global_load_lds(
                (const __attribute__((address_space(1))) unsigned*)ga1,
                (__attribute__((address_space(3))) unsigned*)(As + (size_t)(256 + (w << 6)) * 8), 16, 0, 0);
            const unsigned short* gb0 = Bbase + (size_t)(c0 >> 2) * K + k0 + (c0 & 3) * 8;
            const unsigned short* gb1 = Bbase + (size_t)(c1 >> 2) * K + k0 + (c1 & 3) * 8;
            __builtin_amdgcn_global_load_lds(
                (const __attribute__((address_space(1))) unsigned*)gb0,
                (__attribute__((address_space(3))) unsigned*)(Bs + (size_t)(w << 6) * 8), 16, 0, 0);
            __builtin_amdgcn_global_load_lds(
                (const __attribute__((address_space(1))) unsigned*)gb1,
                (__attribute__((address_space(3))) unsigned*)(Bs + (size_t)(256 + (w << 6)) * 8), 16, 0, 0);
        }
        __syncthreads();

        bf16x8 a[4], b[4];
#pragma unroll
        for (int t = 0; t < 4; ++t)
            a[t] = *(const bf16x8*)&As[(wm + t * 16 + frow) * 32 + fk];
#pragma unroll
        for (int t = 0; t < 4; ++t)
            b[t] = *(const bf16x8*)&Bs[(wn + t * 16 + frow) * 32 + fk];
#pragma unroll
        for (int i = 0; i < 4; ++i)
#pragma unroll
            for (int j = 0; j < 4; ++j)
                acc[i][j] = __builtin_amdgcn_mfma_f32_16x16x32_bf16(a[i], b[j], acc[i][j], 0, 0, 0);
    }

    // epilogue: C/D layout col=lane&15, row=(lane>>4)*4+reg
#pragma unroll
    for (int i = 0; i < 4; ++i) {
        const int gmb = m0 + wm + i * 16 + (lane >> 4) * 4;
#pragma unroll
        for (int j = 0; j < 4; ++j) {
            const int gn = n0 + wn + j * 16 + (lane & 15);
            const int which = SPLIT ? (gn >> 9) : 0;
            const int ln    = SPLIT ? (gn & 511) : gn;
            const int ldo   = SPLIT ? 512 : N;
            const float* bb = (which == 0) ? b0 : ((which == 1) ? b1 : b2);
            void* oo        = (which == 0) ? o0 : ((which == 1) ? o1 : o2);
            const float bv = bb[ln];
#pragma unroll
            for (int r = 0; r < 4; ++r) {
                float cv = acc[i][j][r] + bv;
                if (ACT) cv = gelu_exact(cv);
                if (RES) cv += res[(size_t)(gmb + r) * 512 + gn];
                if (OBF) ((unsigned short*)oo)[(size_t)(gmb + r) * ldo + ln] = f2bf(cv);
                else     ((float*)oo)[(size_t)(gmb + r) * ldo + ln] = cv;
            }
        }
    }
}

// ---------------------------------------------------------------------------
// Transpose + fp32->bf16 convert: src [R,Cc] fp32 -> dst [Cc,R] bf16.
// 64x64 tiles, z = layer (slay/dlay element strides).
// ---------------------------------------------------------------------------
__global__ __launch_bounds__(256) void tconv_k(
    const float* __restrict__ src, unsigned short* __restrict__ dst,
    int R, int Cc, long slay, long dlay)
{
    __shared__ float tile[64][65];
    const int t = threadIdx.x;
    src += (size_t)blockIdx.z * slay;
    dst += (size_t)blockIdx.z * dlay;
    const int r0 = blockIdx.y * 64, c0 = blockIdx.x * 64;
    const int tr = t >> 4, tc = (t & 15) * 4;
#pragma unroll
    for (int i = 0; i < 4; ++i) {
        float4 v = *(const float4*)&src[(size_t)(r0 + tr + i * 16) * Cc + c0 + tc];
        tile[tr + i * 16][tc + 0] = v.x;
        tile[tr + i * 16][tc + 1] = v.y;
        tile[tr + i * 16][tc + 2] = v.z;
        tile[tr + i * 16][tc + 3] = v.w;
    }
    __syncthreads();
#pragma unroll
    for (int i = 0; i < 4; ++i) {
        const int n = tr + i * 16;  // column of src tile = row of dst
        ushort4 o;
        o.x = f2bf(tile[tc + 0][n]);
        o.y = f2bf(tile[tc + 1][n]);
        o.z = f2bf(tile[tc + 2][n]);
        o.w = f2bf(tile[tc + 3][n]);
        *(ushort4*)&dst[(size_t)(c0 + n) * R + r0 + tc] = o;
    }
}

// elementwise fp32 -> bf16 (n multiple of 1024)
__global__ __launch_bounds__(256) void conv_k(
    const float* __restrict__ src, unsigned short* __restrict__ dst)
{
    const int i = (blockIdx.x * 256 + threadIdx.x) * 4;
    float4 v = *(const float4*)&src[i];
    ushort4 o = {f2bf(v.x), f2bf(v.y), f2bf(v.z), f2bf(v.w)};
    *(ushort4*)&dst[i] = o;
}

// ---------------------------------------------------------------------------
// LayerNorm over H=512, bf16 output.
// ---------------------------------------------------------------------------
__global__ __launch_bounds__(256) void ln_k(
    const float* __restrict__ x, const float* __restrict__ g,
    const float* __restrict__ b, unsigned short* __restrict__ out)
{
    const int row = blockIdx.x;
    const int tid = threadIdx.x;
    const float* xr = x + (size_t)row * H_;

    float v0 = xr[tid];
    float v1 = xr[tid + 256];

    float s = v0 + v1;
#pragma unroll
    for (int off = 32; off; off >>= 1) s += __shfl_xor(s, off);

    __shared__ float red[4];
    const int wave = tid >> 6;
    if ((tid & 63) == 0) red[wave] = s;
    __syncthreads();
    const float mean = (red[0] + red[1] + red[2] + red[3]) * (1.0f / (float)H_);

    const float d0 = v0 - mean, d1 = v1 - mean;
    float q = d0 * d0 + d1 * d1;
#pragma unroll
    for (int off = 32; off; off >>= 1) q += __shfl_xor(q, off);
    __syncthreads();
    if ((tid & 63) == 0) red[wave] = q;
    __syncthreads();
    const float var = (red[0] + red[1] + red[2] + red[3]) * (1.0f / (float)H_);
    const float rstd = rsqrtf(var + 1e-5f);

    out[(size_t)row * H_ + tid]       = f2bf(d0 * rstd * g[tid] + b[tid]);
    out[(size_t)row * H_ + tid + 256] = f2bf(d1 * rstd * g[tid + 256] + b[tid + 256]);
}

// ---------------------------------------------------------------------------
// RoPE in-place on fp32 q,k (layout [B,T,H]).
// ---------------------------------------------------------------------------
__global__ __launch_bounds__(256) void rope_k(
    float* __restrict__ q, float* __restrict__ k, const int* __restrict__ ts)
{
    const int idx = blockIdx.x * 256 + threadIdx.x;
    const int d  = idx & 31;
    const int nh = (idx >> 5) & (NH_ - 1);
    const int t  = (idx >> 8) & (T_ - 1);
    const int b  = idx >> 18;

    const int tstamp = ts[b * T_ + t];
    const float inv = expf(-0.2878231366242558f * (float)d);
    const float ang = (float)tstamp * inv;
    const float c = cosf(ang);
    const float s = sinf(ang);

    const size_t base = ((size_t)(b * T_ + t)) * H_ + nh * HD_ + d;
    float q1 = q[base], q2 = q[base + 32];
    q[base]      = q1 * c - q2 * s;
    q[base + 32] = q2 * c + q1 * s;
    float k1 = k[base], k2 = k[base + 32];
    k[base]      = k1 * c - k2 * s;
    k[base + 32] = k2 * c + k1 * s;
}

// ---------------------------------------------------------------------------
// Banded attention (fp32 q,k,v in; bf16 o out).
// ---------------------------------------------------------------------------
#define QT_ 16
#define WR_ (QT_ + CB_)
#define KP_ 68

__global__ __launch_bounds__(256) void attn_k(
    const float* __restrict__ q, const float* __restrict__ k,
    const float* __restrict__ v, const int* __restrict__ smask,
    unsigned short* __restrict__ o)
{
    __shared__ float Ks[WR_][KP_];
    __shared__ float Qs[QT_][KP_];
    __shared__ float S[QT_][WR_ + 2];

    const int blk = blockIdx.x;
    const int qt = blk & (T_ / QT_ - 1);
    const int h  = (blk >> 6) & (NH_ - 1);
    const int b  = blk >> 9;
    const int tid = threadIdx.x;

    const int qlo = qt * QT_;
    const int klo = (qlo - CB_ > 0) ? (qlo - CB_) : 0;
    const int nrows = qlo + QT_ - klo;

    const size_t bhbase = (size_t)(b * T_) * H_ + h * HD_;

    for (int idx = tid; idx < nrows * 64; idx += 256) {
        const int r = idx >> 6, d = idx & 63;
        Ks[r][d] = k[bhbase + (size_t)(klo + r) * H_ + d];
    }
    for (int idx = tid; idx < QT_ * 64; idx += 256) {
        const int iq = idx >> 6, d = idx & 63;
        Qs[iq][d] = q[bhbase + (size_t)(qlo + iq) * H_ + d] * 0.125f;
    }
    {
        float* Sf = &S[0][0];
        for (int idx = tid; idx < QT_ * (WR_ + 2); idx += 256) Sf[idx] = 0.0f;
    }
    __syncthreads();

    const int npairs = QT_ * (CB_ + 1);
    for (int p = tid; p < npairs; p += 256) {
        const int iq = p / (CB_ + 1);
        const int rr = p - iq * (CB_ + 1);
        const int i  = qlo + iq;
        const int j  = i - CB_ + rr;
        if (j < 0) continue;
        const int r = j - klo;
        float acc = 0.0f;
        const float* kr = &Ks[r][0];
        const float* qr = &Qs[iq][0];
#pragma unroll
        for (int dq = 0; dq < 16; ++dq) {
            float4 kv = *(const float4*)(kr + dq * 4);
            float4 qv = *(const float4*)(qr + dq * 4);
            acc += kv.x * qv.x + kv.y * qv.y + kv.z * qv.z + kv.w * qv.w;
        }
        S[iq][r] = (smask[b * T_ + j] > 0) ? acc : -3.4e38f;
    }
    __syncthreads();

    const int w = tid >> 6;
    const int lane = tid & 63;

    float rs[4];
#pragma unroll
    for (int c = 0; c < 4; ++c) {
        const int iq = w * 4 + c;
        const int i  = qlo + iq;
        const int r0 = ((i - CB_ > 0) ? (i - CB_) : 0) - klo;
        const int r1 = i - klo;

        float mx = -3.4e38f;
        for (int r = r0 + lane; r <= r1; r += 64) mx = fmaxf(mx, S[iq][r]);
#pragma unroll
        for (int off = 32; off; off >>= 1) mx = fmaxf(mx, __shfl_xor(mx, off));

        float sum = 0.0f;
        for (int r = r0 + lane; r <= r1; r += 64) {
            float e = expf(S[iq][r] - mx);
            S[iq][r] = e;
            sum += e;
        }
#pragma unroll
        for (int off = 32; off; off >>= 1) sum += __shfl_xor(sum, off);
        rs[c] = 1.0f / sum;
    }

    float od[4] = {0.0f, 0.0f, 0.0f, 0.0f};
    const float* vb = v + bhbase + lane;
    for (int r = 0; r < nrows; ++r) {
        const float vv = vb[(size_t)(klo + r) * H_];
#pragma unroll
        for (int c = 0; c < 4; ++c)
            od[c] += S[w * 4 + c][r] * vv;
    }
#pragma unroll
    for (int c = 0; c < 4; ++c) {
        const int i = qlo + w * 4 + c;
        o[bhbase + (size_t)i * H_ + lane] = f2bf(od[c] * rs[c]);
    }
}

// ---------------------------------------------------------------------------
extern "C" void kernel_launch(void* const* d_in, const int* in_sizes, int n_in,
                              void* d_out, int out_size, void* d_ws, size_t ws_size,
                              hipStream_t stream)
{
    const float* spikes  = (const float*)d_in[0];
    const int*   smask   = (const int*)d_in[1];
    const int*   ts      = (const int*)d_in[2];
    const float* embed_w = (const float*)d_in[3];
    const float* embed_b = (const float*)d_in[4];
    const float* proj_w  = (const float*)d_in[5];
    const float* proj_b  = (const float*)d_in[6];
    const float* ln1_g   = (const float*)d_in[7];
    const float* ln1_b   = (const float*)d_in[8];
    const float* Wq      = (const float*)d_in[9];
    const float* bq      = (const float*)d_in[10];
    const float* Wk      = (const float*)d_in[11];
    const float* bk      = (const float*)d_in[12];
    const float* Wv      = (const float*)d_in[13];
    const float* bv      = (const float*)d_in[14];
    const float* Wo      = (const float*)d_in[15];
    const float* bo      = (const float*)d_in[16];
    const float* ln2_g   = (const float*)d_in[17];
    const float* ln2_b   = (const float*)d_in[18];
    const float* up_w    = (const float*)d_in[19];
    const float* up_b    = (const float*)d_in[20];
    const float* down_w  = (const float*)d_in[21];
    const float* down_b  = (const float*)d_in[22];

    const int M = B_ * T_;  // 4096

    // workspace carve (bytes)
    char* p = (char*)d_ws;
    float* x = (float*)p;                 p += (size_t)M * H_ * 4;        // 8 MB
    float* qbuf = (float*)p;              p += (size_t)M * H_ * 4;
    float* kbuf = (float*)p;              p += (size_t)M * H_ * 4;
    float* vbuf = (float*)p;              p += (size_t)M * H_ * 4;
    unsigned short* hbf   = (unsigned short*)p; p += (size_t)M * H_ * 2;
    unsigned short* obf   = (unsigned short*)p; p += (size_t)M * H_ * 2;
    unsigned short* ibf   = (unsigned short*)p; p += (size_t)M * INTER_ * 2;
    unsigned short* tbf   = (unsigned short*)p; p += (size_t)M * D_ * 2;
    unsigned short* spbf  = (unsigned short*)p; p += (size_t)M * C_ * 2;
    unsigned short* embT  = (unsigned short*)p; p += (size_t)D_ * C_ * 2;
    unsigned short* projT = (unsigned short*)p; p += (size_t)H_ * D_ * 2;
    unsigned short* qkvT  = (unsigned short*)p; p += (size_t)L_ * 3 * H_ * H_ * 2;
    unsigned short* woT   = (unsigned short*)p; p += (size_t)L_ * H_ * H_ * 2;
    unsigned short* upT   = (unsigned short*)p; p += (size_t)L_ * INTER_ * H_ * 2;
    unsigned short* downT = (unsigned short*)p; p += (size_t)L_ * H_ * INTER_ * 2;

    // ---- prologue: convert spikes, transpose+convert all weights ----
    conv_k<<<(M * C_) / 1024, 256, 0, stream>>>(spikes, spbf);
    // embed_w [C,D] -> embT [D,C]
    tconv_k<<<dim3(D_ / 64, C_ / 64, 1), 256, 0, stream>>>(embed_w, embT, C_, D_, 0, 0);
    // proj_w [D,H] -> projT [H,D]
    tconv_k<<<dim3(H_ / 64, D_ / 64, 1), 256, 0, stream>>>(proj_w, projT, D_, H_, 0, 0);
    // Wq/Wk/Wv [L,H,H] -> qkvT [L][1536,H] (q rows 0..511, k 512..1023, v 1024..1535)
    tconv_k<<<dim3(H_ / 64, H_ / 64, L_), 256, 0, stream>>>(
        Wq, qkvT,            H_, H_, (long)H_ * H_, (long)3 * H_ * H_);
    tconv_k<<<dim3(H_ / 64, H_ / 64, L_), 256, 0, stream>>>(
        Wk, qkvT + H_ * H_,  H_, H_, (long)H_ * H_, (long)3 * H_ * H_);
    tconv_k<<<dim3(H_ / 64, H_ / 64, L_), 256, 0, stream>>>(
        Wv, qkvT + 2 * H_ * H_, H_, H_, (long)H_ * H_, (long)3 * H_ * H_);
    // Wo [L,H,H] -> woT
    tconv_k<<<dim3(H_ / 64, H_ / 64, L_), 256, 0, stream>>>(
        Wo, woT, H_, H_, (long)H_ * H_, (long)H_ * H_);
    // up_w [L,H,INTER] -> upT [L][INTER,H]
    tconv_k<<<dim3(INTER_ / 64, H_ / 64, L_), 256, 0, stream>>>(
        up_w, upT, H_, INTER_, (long)H_ * INTER_, (long)INTER_ * H_);
    // down_w [L,INTER,H] -> downT [L][H,INTER]
    tconv_k<<<dim3(H_ / 64, INTER_ / 64, L_), 256, 0, stream>>>(
        down_w, downT, INTER_, H_, (long)INTER_ * H_, (long)H_ * INTER_);

    // ---- embedding: tmp = gelu(spikes @ embed_w + b) ; x = tmp @ proj_w + b ----
    mm_k<1, 0, 1, 0><<<dim3(D_ / 128, M / 128), 256, 0, stream>>>(
        spbf, embT, embed_b, nullptr, nullptr, nullptr, tbf, nullptr, nullptr, M, D_, C_);
    mm_k<0, 0, 0, 0><<<dim3(H_ / 128, M / 128), 256, 0, stream>>>(
        tbf, projT, proj_b, nullptr, nullptr, nullptr, x, nullptr, nullptr, M, H_, D_);

    for (int l = 0; l < L_; ++l) {
        const unsigned short* qkvT_l = qkvT + (size_t)l * 3 * H_ * H_;
        const unsigned short* woT_l  = woT  + (size_t)l * H_ * H_;
        const unsigned short* upT_l  = upT  + (size_t)l * INTER_ * H_;
        const unsigned short* dnT_l  = downT + (size_t)l * H_ * INTER_;

        ln_k<<<M, 256, 0, stream>>>(x, ln1_g + l * H_, ln1_b + l * H_, hbf);

        // fused QKV: N = 1536, route by col>>9
        mm_k<0, 0, 0, 1><<<dim3((3 * H_) / 128, M / 128), 256, 0, stream>>>(
            hbf, qkvT_l, bq + l * H_, bk + l * H_, bv + l * H_, nullptr,
            qbuf, kbuf, vbuf, M, 3 * H_, H_);

        rope_k<<<(B_ * T_ * NH_ * 32) / 256, 256, 0, stream>>>(qbuf, kbuf, ts);

        attn_k<<<B_ * NH_ * (T_ / QT_), 256, 0, stream>>>(qbuf, kbuf, vbuf, smask, obf);

        // x = x + obuf @ Wo + bo
        mm_k<0, 1, 0, 0><<<dim3(H_ / 128, M / 128), 256, 0, stream>>>(
            obf, woT_l, bo + l * H_, nullptr, nullptr, x, x, nullptr, nullptr, M, H_, H_);

        ln_k<<<M, 256, 0, stream>>>(x, ln2_g + l * H_, ln2_b + l * H_, hbf);

        // inter = gelu(h @ up_w + b)
        mm_k<1, 0, 1, 0><<<dim3(INTER_ / 128, M / 128), 256, 0, stream>>>(
            hbf, upT_l, up_b + l * INTER_, nullptr, nullptr, nullptr,
            ibf, nullptr, nullptr, M, INTER_, H_);

        // x = x + inter @ down_w + b   (last layer -> d_out)
        float* dst = (l == L_ - 1) ? (float*)d_out : x;
        mm_k<0, 1, 0, 0><<<dim3(H_ / 128, M / 128), 256, 0, stream>>>(
            ibf, dnT_l, down_b + l * H_, nullptr, nullptr, x, dst, nullptr, nullptr,
            M, H_, INTER_);
    }
}